// Round 5
// baseline (895.655 us; speedup 1.0000x reference)
//
#include <hip/hip_runtime.h>
#include <hip/hip_bf16.h>
#include <stdint.h>

#define LSEQ 197
#define NH   12
#define HD   64
#define CDIM 768
#define QKVS 2304   // fused Q|K|V row stride

#define VSTRD 200   // V^T rows: 100 dw -> lanes i,i+8 share bank = 2-way (free)

typedef __bf16 bf16x8 __attribute__((ext_vector_type(8)));
typedef float  f32x4  __attribute__((ext_vector_type(4)));
typedef unsigned short u16x4 __attribute__((ext_vector_type(4)));

__device__ __forceinline__ float bf2f(unsigned short u) { return __uint_as_float(((unsigned)u) << 16); }
__device__ __forceinline__ unsigned short f2bf(float f) {
  unsigned u = __float_as_uint(f);
  unsigned r = 0x7fffu + ((u >> 16) & 1u);
  return (unsigned short)((u + r) >> 16);
}

__device__ __forceinline__ void gload16(const void* g, void* l) {
  __builtin_amdgcn_global_load_lds(
      (const __attribute__((address_space(1))) unsigned int*)(g),
      (__attribute__((address_space(3))) unsigned int*)(l), 16, 0, 0);
}

__device__ __forceinline__ bf16x8 pack4(unsigned x, unsigned y, unsigned z, unsigned w) {
  union { unsigned u[4]; bf16x8 v; } t;
  t.u[0] = x; t.u[1] = y; t.u[2] = z; t.u[3] = w;
  return t.v;
}

// ------------------------------------------------------------ dtype detect
__global__ void detect_dtype(const unsigned* __restrict__ x, int* __restrict__ flag) {
  __shared__ int cnt;
  if (threadIdx.x == 0) cnt = 0;
  __syncthreads();
  int local = 0;
  for (int i = threadIdx.x; i < 1024; i += 256) {
    const unsigned e = (x[i] >> 7) & 0xFFu;
    if (e >= 96u && e <= 140u) local++;
  }
  atomicAdd(&cnt, local);
  __syncthreads();
  if (threadIdx.x == 0) *flag = (cnt > 512) ? 0 : 1;
}

// --------------------------------------------------------- bulk conversion
__global__ void convert_to_bf16(const void* __restrict__ in,
                                unsigned short* __restrict__ outb,
                                const int* __restrict__ flag, long n) {
  const long stride = (long)gridDim.x * blockDim.x;
  long i = (long)blockIdx.x * blockDim.x + threadIdx.x;
  if (*flag) {
    const float* f = (const float*)in;
    for (; i < n; i += stride) outb[i] = f2bf(f[i]);
  } else {
    const unsigned short* s = (const unsigned short*)in;
    for (; i < n; i += stride) outb[i] = s[i];
  }
}

// ------------------------------------------------- small tensors (one kernel)
// packed u16: bq@0 bk@768 bv@1536 bo@2304 rel@3072 c2p@11820 p2c@14172 c2c@16524
__global__ void convert_small(const void* b0, const void* b1, const void* b2, const void* b3,
                              const void* r, const void* cp, const void* pc, const void* cc,
                              unsigned short* __restrict__ out, const int* __restrict__ flag) {
  const int starts[9] = {0, 768, 1536, 2304, 3072, 11820, 14172, 16524, 16536};
  const void* srcs[8] = {b0, b1, b2, b3, r, cp, pc, cc};
  const bool isf = (*flag != 0);
  for (int i = blockIdx.x * blockDim.x + threadIdx.x; i < 16536;
       i += gridDim.x * blockDim.x) {
    int seg = 0;
    while (i >= starts[seg + 1]) seg++;
    const int off = i - starts[seg];
    out[i] = isf ? f2bf(((const float*)srcs[seg])[off])
                 : ((const unsigned short*)srcs[seg])[off];
  }
}

// ---------------------------------------------------- bias frag-table precompute
// Lane-major quad layout, bf16: biasB[((h*13+mt)*13+nt)*256 + lane*4 + r]
// (pre-multiplied by log2e; -1e30 where q or k out of range). One dwordx2 per
// lane per nt = fully coalesced 512-B load. Frag map (swapped-QK S^T):
//   q = mt*16 + (lane&15), k = nt*16 + (lane>>4)*4 + r.
__global__ void bias_build(const unsigned short* __restrict__ sm,
                           unsigned short* __restrict__ biasB) {
  const int gid = blockIdx.x * blockDim.x + threadIdx.x;
  if (gid >= 12 * 13 * 13 * 256) return;
  const int r    = gid & 3;
  const int lane = (gid >> 2) & 63;
  const int t    = gid >> 8;          // (h*13 + mt)*13 + nt
  const int nt   = t % 13;
  const int mt   = (t / 13) % 13;
  const int h    = t / 169;
  const int q = mt * 16 + (lane & 15);
  const int k = nt * 16 + ((lane >> 4) & 3) * 4 + r;
  float v;
  if (q >= 197 || k >= 197) {
    v = -1e30f;
  } else {
    const unsigned short* rel = sm + 3072;
    const unsigned short* c2p = sm + 11820;
    const unsigned short* p2c = sm + 14172;
    const unsigned short* c2c = sm + 16524;
    unsigned short u;
    if (q == 0) {
      u = (k == 0) ? c2c[h] : c2p[h * 196 + (k - 1)];
    } else if (k == 0) {
      u = p2c[h * 196 + (q - 1)];
    } else {
      const int pi = q - 1, pj = k - 1;
      const int dh = pi / 14 - pj / 14 + 13;
      const int dw = pi % 14 - pj % 14 + 13;
      u = rel[(dh * 27 + dw) * 12 + h];
    }
    v = bf2f(u) * 1.4426950408889634f;
  }
  biasB[gid] = f2bf(v);
}

// ------------------------------------------------- transpose 768x768 + cvt
__global__ void transpose768_cvt(const void* __restrict__ in,
                                 unsigned short* __restrict__ out,
                                 const int* __restrict__ flag) {
  __shared__ unsigned short tile[32][33];
  const bool isf = (*flag != 0);
  const int tx = threadIdx.x & 31;
  const int ty = threadIdx.x >> 5;
  const int bx = blockIdx.x, by = blockIdx.y;
#pragma unroll
  for (int j = 0; j < 32; j += 8) {
    const size_t idx = (size_t)(by * 32 + ty + j) * CDIM + bx * 32 + tx;
    tile[ty + j][tx] = isf ? f2bf(((const float*)in)[idx])
                           : ((const unsigned short*)in)[idx];
  }
  __syncthreads();
#pragma unroll
  for (int j = 0; j < 32; j += 8)
    out[(size_t)(bx * 32 + ty + j) * CDIM + by * 32 + tx] = tile[tx][ty + j];
}

// ------------------------------------------------------------------- GEMM
// 1-D grid, bijective XCD-chunked remap (m204). K-loop is a 2-deep prefetch
// pipeline with COUNTED vmcnt (T3+T4): iter t stages tile t+2 into buf[(t+2)%3]
// while computing buf[t%3]; end-of-iter waits vmcnt(4) (tile t+1's loads) and
// crosses a raw s_barrier with tile t+2's loads still in flight. vmcnt(0)
// never appears in the steady-state loop.
__global__ __launch_bounds__(256, 2) void gemm_bt_bias(
    const unsigned short* __restrict__ A,
    const unsigned short* __restrict__ Bt,
    const unsigned short* __restrict__ bias,
    void* __restrict__ C,
    int M, int N, int K,
    const int* __restrict__ outf32) {
  __shared__ unsigned short As[3][128 * 32];   // 3 x 8 KB
  __shared__ unsigned short Bs[3][128 * 32];   // 3 x 8 KB   (48 KB total)

  const int tid  = threadIdx.x;
  const int lane = tid & 63;
  const int wid  = tid >> 6;
  // XCD-aware bijective remap (nwg % 8 != 0 safe)
  const int nwg = gridDim.x;
  const int q8 = nwg >> 3, r8 = nwg & 7;
  const int xcd = blockIdx.x & 7, ii = blockIdx.x >> 3;
  const int wg = (xcd < r8 ? xcd * (q8 + 1) : r8 * (q8 + 1) + (xcd - r8) * q8) + ii;
  const int nbn = N >> 7;
  const int bm = wg / nbn, bn = wg % nbn;
  const int wm = wid >> 1, wn = wid & 1;
  const bool wf32 = (outf32 != nullptr) && (*outf32 != 0);

  const int srow = (wid * 2) * 16 + (lane >> 2);
  const int scol = (lane & 3) * 8;
  const unsigned short* Ag = A  + (size_t)(bm * 128 + srow) * K + scol;
  const unsigned short* Bg = Bt + (size_t)(bn * 128 + srow) * K + scol;
  const int swave = (wid * 2) * 16 * 32;      // wave's 32-row stage region

  f32x4 acc[4][4] = {};
  const int nt = K >> 5;                      // 24 for K=768

#define STAGE(bufi) do {                                         \
    gload16(Ag, &As[bufi][swave]);                               \
    gload16(Ag + (size_t)16 * K, &As[bufi][swave + 512]);        \
    gload16(Bg, &Bs[bufi][swave]);                               \
    gload16(Bg + (size_t)16 * K, &Bs[bufi][swave + 512]);        \
    Ag += 32; Bg += 32; } while (0)

#define COMPUTE(bufi) do {                                                         \
    bf16x8 fa[4], fb[4];                                                           \
    _Pragma("unroll")                                                              \
    for (int t4 = 0; t4 < 4; ++t4) {                                               \
      fa[t4] = *(const bf16x8*)&As[bufi][(wm * 64 + t4 * 16 + (lane & 15)) * 32 + (lane >> 4) * 8]; \
      fb[t4] = *(const bf16x8*)&Bs[bufi][(wn * 64 + t4 * 16 + (lane & 15)) * 32 + (lane >> 4) * 8]; \
    }                                                                              \
    _Pragma("unroll")                                                              \
    for (int mt = 0; mt < 4; ++mt)                                                 \
      _Pragma("unroll")                                                            \
      for (int ntt = 0; ntt < 4; ++ntt)                                            \
        acc[mt][ntt] = __builtin_amdgcn_mfma_f32_16x16x32_bf16(fa[mt], fb[ntt], acc[mt][ntt], 0, 0, 0); \
    } while (0)

  // prologue: stage tiles 0 and 1; wait tile 0 only (tile 1 stays in flight)
  STAGE(0);
  STAGE(1);
  asm volatile("s_waitcnt vmcnt(4)" ::: "memory");
  __builtin_amdgcn_s_barrier();

#pragma unroll 3
  for (int t = 0; t < nt; ++t) {
    if (t + 2 < nt) STAGE((t + 2) % 3);
    __builtin_amdgcn_sched_barrier(0);      // pin stage-issue before compute
    COMPUTE(t % 3);
    if (t + 1 < nt) {
      if (t + 2 < nt) asm volatile("s_waitcnt vmcnt(4)" ::: "memory");
      else            asm volatile("s_waitcnt vmcnt(0)" ::: "memory");
      __builtin_amdgcn_s_barrier();
    }
  }
#undef STAGE
#undef COMPUTE

  // bias per nt-column (hoisted)
  float bvv[4];
#pragma unroll
  for (int c = 0; c < 4; ++c)
    bvv[c] = bf2f(bias[bn * 128 + wn * 64 + c * 16 + (lane & 15)]);

#pragma unroll
  for (int mt = 0; mt < 4; ++mt) {
    const int row0 = bm * 128 + wm * 64 + mt * 16 + (lane >> 4) * 4;
#pragma unroll
    for (int r = 0; r < 4; ++r) {
      const size_t rowoff = (size_t)(row0 + r) * N + bn * 128 + wn * 64 + (lane & 15);
#pragma unroll
      for (int c = 0; c < 4; ++c) {
        const float val = acc[mt][c][r] + bvv[c];
        const size_t idx = rowoff + c * 16;
        if (wf32) ((float*)C)[idx] = val;
        else      ((unsigned short*)C)[idx] = f2bf(val);
      }
    }
  }
}

// ------------------------------------------------------- MFMA attention
// One block per (b,h), b-MAJOR: the 12 heads of one batch run adjacently so
// adjacent 128-B head-segments of each QKV/ctx row are read/written together
// (same L2 granule, same XCD, same time) -> no partial-line thrash.
// Swapped QK^T: s = mfma(K,Q) -> S^T frag (q = lane&15, k = nt*16 + g*4 + r).
// Softmax row lives in 4 lanes -> 2 shfl_xor per reduce; exp2-domain logits.
// P -> A-frag via cvt_pk_bf16 + ds_bpermute (no LDS round-trip, no fences).
// LDS 52.2 KB -> 3 blocks/CU.
__global__ __launch_bounds__(256, 3) void attn_mfma(
    const unsigned short* __restrict__ QKV,
    const unsigned short* __restrict__ biasB,
    unsigned short* __restrict__ ctx) {
  __shared__ unsigned short Kh[208 * 64];   // 26,624 B: 128-B rows, XOR-swizzled
  __shared__ unsigned short Vt[64 * VSTRD]; // 25,600 B: V^T [d][k], k-pad 200

  const int tid  = threadIdx.x;
  const int lane = tid & 63;
  const int wid  = tid >> 6;
  const int bh = blockIdx.x;
  const int b = bh / NH;          // b-major
  const int h = bh - b * NH;
  const size_t baseQ = (size_t)b * LSEQ * QKVS + (size_t)h * HD;
  const size_t baseK = baseQ + 768;
  const size_t baseV = baseQ + 1536;
  const size_t baseC = (size_t)b * LSEQ * CDIM + (size_t)h * HD;

  // stage K: packed 128-B rows, byte ^= (row&7)<<4 (2-way conflicts = free,
  // write pattern rows l..l+7 covers all 32 banks conflict-free)
  for (int i = tid; i < 197 * 8; i += 256) {
    const int l = i >> 3, c8 = (i & 7) * 8;
    const bf16x8 kv = *(const bf16x8*)&QKV[baseK + (size_t)l * QKVS + c8];
    *(bf16x8*)((char*)Kh + l * 128 + ((c8 * 2) ^ ((l & 7) << 4))) = kv;
  }
  // stage V^T
  for (int i = tid; i < 197 * 32; i += 256) {
    const int l = i >> 5, d2 = (i & 31) * 2;
    const unsigned vv = *(const unsigned*)&QKV[baseV + (size_t)l * QKVS + d2];
    Vt[d2 * VSTRD + l]       = (unsigned short)(vv & 0xffffu);
    Vt[(d2 + 1) * VSTRD + l] = (unsigned short)(vv >> 16);
  }
  // zero V^T pad cols k = 197..199 (t=6 tail reads k 192..199; P=0 past 196)
  for (int i = tid; i < 64 * 3; i += 256)
    Vt[(i / 3) * VSTRD + 197 + (i % 3)] = 0;
  __syncthreads();

  const int ql = lane & 15, g = lane >> 4;
  // K A-frag byte bases (swizzled); per-nt offset is the imm 2048*nt
  const int krd0 = ql * 128 + ((g * 16) ^ ((ql & 7) << 4));
  const int krd1 = ql * 128 + ((g * 16 + 64) ^ ((ql & 7) << 4));
  // V^T B-frag u16 bases
  const int vrd  = ql * VSTRD + g * 8;
  const int vrd6 = ql * VSTRD + 192;      // t=6 tail: clamp k-chunk to 192
  // bpermute source-lane byte addrs: g2a = 2*(g&1), g2b = g2a+1 (same q)
  const int addrA = (((g & 1) << 5) + ql) << 2;
  const int addrB = addrA + 64;
  const bool hi2 = lane >= 32;            // g >= 2
  const bool hi1 = lane >= 16;            // g >= 1

  for (int mt = wid; mt < 13; mt += 4) {
    // Q B-frags (global, 16B aligned; pad rows clamped to 196)
    const int qm = mt * 16 + ql;
    const unsigned short* qp =
        &QKV[baseQ + (size_t)(qm > 196 ? 196 : qm) * QKVS + g * 8];
    const bf16x8 qf0 = *(const bf16x8*)qp;
    const bf16x8 qf1 = *(const bf16x8*)(qp + 32);

    // bias quads: 13 coalesced dwordx2 bf16 (issued before MFMAs)
    const unsigned short* bp =
        biasB + (size_t)(h * 13 + mt) * 13 * 256 + (lane << 2);
    u16x4 bq[13];
#pragma unroll
    for (int nt = 0; nt < 13; ++nt) bq[nt] = *(const u16x4*)(bp + nt * 256);

    // S^T = K Q^T  (13 nt-tiles x 2 MFMAs)
    f32x4 s[13];
#pragma unroll
    for (int nt = 0; nt < 13; ++nt) {
      const bf16x8 kb0 = *(const bf16x8*)((const char*)Kh + nt * 2048 + krd0);
      const bf16x8 kb1 = *(const bf16x8*)((const char*)Kh + nt * 2048 + krd1);
      f32x4 a = {0.f, 0.f, 0.f, 0.f};
      a = __builtin_amdgcn_mfma_f32_16x16x32_bf16(kb0, qf0, a, 0, 0, 0);
      a = __builtin_amdgcn_mfma_f32_16x16x32_bf16(kb1, qf1, a, 0, 0, 0);
      s[nt] = a;
    }

    // log2-domain logits: s*(0.125*log2e) + bias*log2e
#pragma unroll
    for (int nt = 0; nt < 13; ++nt)
#pragma unroll
      for (int r = 0; r < 4; ++r)
        s[nt][r] = s[nt][r] * 0.18033688011112042f + bf2f(bq[nt][r]);

    // kill garbage K rows (k>=197 at nt=12) -- NaN-proof overwrite
    const float NEG = -1e30f;
    s[12][0] = hi2 ? NEG : s[12][0];
    s[12][1] = hi1 ? NEG : s[12][1];
    s[12][2] = hi1 ? NEG : s[12][2];
    s[12][3] = hi1 ? NEG : s[12][3];

    // exact softmax: row q spread over lanes {q, q+16, q+32, q+48}
    float m0 = s[0][0], m1 = s[0][1], m2 = s[0][2], m3 = s[0][3];
#pragma unroll
    for (int nt = 1; nt < 13; ++nt) {
      m0 = fmaxf(m0, s[nt][0]); m1 = fmaxf(m1, s[nt][1]);
      m2 = fmaxf(m2, s[nt][2]); m3 = fmaxf(m3, s[nt][3]);
    }
    float m = fmaxf(fmaxf(m0, m1), fmaxf(m2, m3));
    m = fmaxf(m, __shfl_xor(m, 16));
    m = fmaxf(m, __shfl_xor(m, 32));
    float t0 = 0.f, t1 = 0.f, t2 = 0.f, t3 = 0.f;
#pragma unroll
    for (int nt = 0; nt < 13; ++nt) {
      s[nt][0] = __builtin_exp2f(s[nt][0] - m); t0 += s[nt][0];
      s[nt][1] = __builtin_exp2f(s[nt][1] - m); t1 += s[nt][1];
      s[nt][2] = __builtin_exp2f(s[nt][2] - m); t2 += s[nt][2];
      s[nt][3] = __builtin_exp2f(s[nt][3] - m); t3 += s[nt][3];
    }
    float sum = (t0 + t1) + (t2 + t3);
    sum += __shfl_xor(sum, 16);
    sum += __shfl_xor(sum, 32);
    const float inv = __builtin_amdgcn_rcpf(sum);

    // normalize + pack P to bf16 pairs (k-adjacent): pk0 = (r0,r1), pk1 = (r2,r3)
    unsigned pk0[13], pk1[13];
#pragma unroll
    for (int nt = 0; nt < 13; ++nt) {
      const float p0 = s[nt][0] * inv, p1 = s[nt][1] * inv;
      const float p2 = s[nt][2] * inv, p3 = s[nt][3] * inv;
      unsigned lo, hi;
      asm("v_cvt_pk_bf16_f32 %0, %1, %2" : "=v"(lo) : "v"(p0), "v"(p1));
      asm("v_cvt_pk_bf16_f32 %0, %1, %2" : "=v"(hi) : "v"(p2), "v"(p3));
      pk0[nt] = lo; pk1[nt] = hi;
    }

    // O = P V : A-frag lane (g,q) needs k = t*32+g*8+j from lanes (2(g&1)(+1), q),
    // register nt = 2t + (g>>1) -> bpermute both nt candidates, select by hi2.
    f32x4 o[4] = {{0.f,0.f,0.f,0.f},{0.f,0.f,0.f,0.f},{0.f,0.f,0.f,0.f},{0.f,0.f,0.f,0.f}};
#pragma unroll
    for (int t = 0; t < 6; ++t) {
      const int i0 = 2 * t, i1 = 2 * t + 1;
      const int xA0 = __builtin_amdgcn_ds_bpermute(addrA, (int)pk0[i0]);
      const int yA0 = __builtin_amdgcn_ds_bpermute(addrA, (int)pk0[i1]);
      const int xA1 = __builtin_amdgcn_ds_bpermute(addrA, (int)pk1[i0]);
      const int yA1 = __builtin_amdgcn_ds_bpermute(addrA, (int)pk1[i1]);
      const int xB0 = __builtin_amdgcn_ds_bpermute(addrB, (int)pk0[i0]);
      const int yB0 = __builtin_amdgcn_ds_bpermute(addrB, (int)pk0[i1]);
      const int xB1 = __builtin_amdgcn_ds_bpermute(addrB, (int)pk1[i0]);
      const int yB1 = __builtin_amdgcn_ds_bpermute(addrB, (int)pk1[i1]);
      const bf16x8 pa = pack4((unsigned)(hi2 ? yA0 : xA0),
                              (unsigned)(hi2 ? yA1 : xA1),
                              (unsigned)(hi2 ? yB0 : xB0),
                              (unsigned)(hi2 ? yB1 : xB1));
#pragma unroll
      for (int ot = 0; ot < 4; ++ot) {
        const bf16x8 vbf = *(const bf16x8*)&Vt[ot * 16 * VSTRD + vrd + t * 32];
        o[ot] = __builtin_amdgcn_mfma_f32_16x16x32_bf16(pa, vbf, o[ot], 0, 0, 0);
      }
    }
    { // tail t=6: nt=12 only; g>=2 lanes are all-masked (P=0)
      const int xA0 = __builtin_amdgcn_ds_bpermute(addrA, (int)pk0[12]);
      const int xA1 = __builtin_amdgcn_ds_bpermute(addrA, (int)pk1[12]);
      const int xB0 = __builtin_amdgcn_ds_bpermute(addrB, (int)pk0[12]);
      const int xB1 = __builtin_amdgcn_ds_bpermute(addrB, (int)pk1[12]);
      const bf16x8 pa = pack4(hi2 ? 0u : (unsigned)xA0,
                              hi2 ? 0u : (unsigned)xA1,
                              hi2 ? 0u : (unsigned)xB0,
                              hi2 ? 0u : (unsigned)xB1);
#pragma unroll
      for (int ot = 0; ot < 4; ++ot) {
        const bf16x8 vbf = *(const bf16x8*)&Vt[ot * 16 * VSTRD + vrd6];
        o[ot] = __builtin_amdgcn_mfma_f32_16x16x32_bf16(pa, vbf, o[ot], 0, 0, 0);
      }
    }

    // store: complete each 128-B line (row q) in 4 consecutive 32-B stores
#pragma unroll
    for (int r = 0; r < 4; ++r) {
      const int q = mt * 16 + g * 4 + r;
      if (q < LSEQ) {
#pragma unroll
        for (int ot = 0; ot < 4; ++ot)
          ctx[baseC + (size_t)q * CDIM + ot * 16 + ql] = f2bf(o[ot][r]);
      }
    }
  }
}

// ------------------------------------------------------------------ launch
extern "C" void kernel_launch(void* const* d_in, const int* in_sizes, int n_in,
                              void* d_out, int out_size, void* d_ws, size_t ws_size,
                              hipStream_t stream) {
  const void* X   = d_in[0];
  const void* Wq  = d_in[1];
  const void* bq  = d_in[2];
  const void* Wk  = d_in[3];
  const void* bk  = d_in[4];
  const void* Wv  = d_in[5];
  const void* bv  = d_in[6];
  const void* Wo  = d_in[7];
  const void* bo  = d_in[8];
  const void* rel = d_in[9];
  const void* c2p = d_in[10];
  const void* p2c = d_in[11];
  const void* c2c = d_in[12];

  char* ws = (char*)d_ws;
  const size_t FLAG_OFF = 0;
  const size_t SM_OFF   = 256;                       // 16536 u16 = 33,072 B
  const size_t BIAS_OFF = 40960;                     // biasB: 519,168 u16 = 1,038,336 B
  const size_t WT_OFF   = BIAS_OFF + 2080768;        // aligned
  const size_t WT_SZ    = (size_t)CDIM * CDIM * 2;   // 1,179,648 B
  const size_t XB_OFF   = WT_OFF + 4 * WT_SZ;
  const size_t X_SZ     = (size_t)50432 * CDIM * 2;  // 77,463,552 B
  const size_t QKV_OFF  = XB_OFF + X_SZ;             // 50432*2304*2 = 232,390,656 B
  int* flag = (int*)(ws + FLAG_OFF);
  unsigned short* smb   = (unsigned short*)(ws + SM_OFF);
  unsigned short* biasB = (unsigned short*)(ws + BIAS_OFF);
  unsigned short* WqT = (unsigned short*)(ws + WT_OFF + 0 * WT_SZ);  // WqT|WkT|WvT
  unsigned short* WkT = (unsigned short*)(ws + WT_OFF + 1 * WT_SZ);  //   contiguous =
  unsigned short* WvT = (unsigned short*)(ws + WT_OFF + 2 * WT_SZ);  //   [2304][768]
  unsigned short* WoT = (unsigned short*)(ws + WT_OFF + 3 * WT_SZ);
  unsigned short* Xb  = (unsigned short*)(ws + XB_OFF);
  unsigned short* QKVb= (unsigned short*)(ws + QKV_OFF);
  unsigned short* Cb  = Xb;   // Xb dead after the QKV GEMM — reuse for ctx

  detect_dtype<<<1, 256, 0, stream>>>((const unsigned*)X, flag);

  convert_to_bf16<<<4096, 256, 0, stream>>>(X, Xb, flag, (long)50432 * CDIM);
  convert_small<<<65, 256, 0, stream>>>(bq, bk, bv, bo, rel, c2p, p2c, c2c, smb, flag);
  bias_build<<<2028, 256, 0, stream>>>(smb, biasB);

  dim3 tgrid(24, 24);
  transpose768_cvt<<<tgrid, 256, 0, stream>>>(Wq, WqT, flag);
  transpose768_cvt<<<tgrid, 256, 0, stream>>>(Wk, WkT, flag);
  transpose768_cvt<<<tgrid, 256, 0, stream>>>(Wv, WvT, flag);
  transpose768_cvt<<<tgrid, 256, 0, stream>>>(Wo, WoT, flag);

  // fused QKV GEMM: Bt = [WqT|WkT|WvT] (contiguous), bias = [bq|bk|bv] (contiguous)
  gemm_bt_bias<<<dim3(18 * 394), 256, 0, stream>>>(Xb, WqT, smb, QKVb,
                                                   50432, QKVS, CDIM, nullptr);

  attn_mfma<<<dim3(256 * NH), 256, 0, stream>>>(QKVb, biasB, Cb);

  gemm_bt_bias<<<dim3(6 * 394), 256, 0, stream>>>(Cb, WoT, smb + 2304, d_out,
                                                  50432, CDIM, CDIM, flag);
}

// Round 6
// 826.283 us; speedup vs baseline: 1.0840x; 1.0840x over previous
//
#include <hip/hip_runtime.h>
#include <hip/hip_bf16.h>
#include <stdint.h>

#define LSEQ 197
#define NH   12
#define HD   64
#define CDIM 768
#define QKVS 2304   // fused Q|K|V row stride

#define VSTRD 200   // V^T rows: 100 dw -> lanes i,i+8 share bank = 2-way (free)

typedef __bf16 bf16x8 __attribute__((ext_vector_type(8)));
typedef float  f32x4  __attribute__((ext_vector_type(4)));
typedef unsigned short u16x4 __attribute__((ext_vector_type(4)));

__device__ __forceinline__ float bf2f(unsigned short u) { return __uint_as_float(((unsigned)u) << 16); }
__device__ __forceinline__ unsigned short f2bf(float f) {
  unsigned u = __float_as_uint(f);
  unsigned r = 0x7fffu + ((u >> 16) & 1u);
  return (unsigned short)((u + r) >> 16);
}

__device__ __forceinline__ void gload16(const void* g, void* l) {
  __builtin_amdgcn_global_load_lds(
      (const __attribute__((address_space(1))) unsigned int*)(g),
      (__attribute__((address_space(3))) unsigned int*)(l), 16, 0, 0);
}

__device__ __forceinline__ bf16x8 pack4(unsigned x, unsigned y, unsigned z, unsigned w) {
  union { unsigned u[4]; bf16x8 v; } t;
  t.u[0] = x; t.u[1] = y; t.u[2] = z; t.u[3] = w;
  return t.v;
}

// ------------------------------------------------------------ dtype detect
__global__ void detect_dtype(const unsigned* __restrict__ x, int* __restrict__ flag) {
  __shared__ int cnt;
  if (threadIdx.x == 0) cnt = 0;
  __syncthreads();
  int local = 0;
  for (int i = threadIdx.x; i < 1024; i += 256) {
    const unsigned e = (x[i] >> 7) & 0xFFu;
    if (e >= 96u && e <= 140u) local++;
  }
  atomicAdd(&cnt, local);
  __syncthreads();
  if (threadIdx.x == 0) *flag = (cnt > 512) ? 0 : 1;
}

// --------------------------------------------------------- bulk conversion
__global__ void convert_to_bf16(const void* __restrict__ in,
                                unsigned short* __restrict__ outb,
                                const int* __restrict__ flag, long n) {
  const long stride = (long)gridDim.x * blockDim.x;
  long i = (long)blockIdx.x * blockDim.x + threadIdx.x;
  if (*flag) {
    const float* f = (const float*)in;
    for (; i < n; i += stride) outb[i] = f2bf(f[i]);
  } else {
    const unsigned short* s = (const unsigned short*)in;
    for (; i < n; i += stride) outb[i] = s[i];
  }
}

// ------------------------------------------------- small tensors (one kernel)
// packed u16: bq@0 bk@768 bv@1536 bo@2304 rel@3072 c2p@11820 p2c@14172 c2c@16524
__global__ void convert_small(const void* b0, const void* b1, const void* b2, const void* b3,
                              const void* r, const void* cp, const void* pc, const void* cc,
                              unsigned short* __restrict__ out, const int* __restrict__ flag) {
  const int starts[9] = {0, 768, 1536, 2304, 3072, 11820, 14172, 16524, 16536};
  const void* srcs[8] = {b0, b1, b2, b3, r, cp, pc, cc};
  const bool isf = (*flag != 0);
  for (int i = blockIdx.x * blockDim.x + threadIdx.x; i < 16536;
       i += gridDim.x * blockDim.x) {
    int seg = 0;
    while (i >= starts[seg + 1]) seg++;
    const int off = i - starts[seg];
    out[i] = isf ? f2bf(((const float*)srcs[seg])[off])
                 : ((const unsigned short*)srcs[seg])[off];
  }
}

// ---------------------------------------------------- bias frag-table precompute
// Lane-major quad layout, bf16: biasB[((h*13+mt)*13+nt)*256 + lane*4 + r]
// (pre-multiplied by log2e; -1e30 where q or k out of range). One dwordx2 per
// lane per nt = fully coalesced 512-B load. Frag map (swapped-QK S^T):
//   q = mt*16 + (lane&15), k = nt*16 + (lane>>4)*4 + r.
__global__ void bias_build(const unsigned short* __restrict__ sm,
                           unsigned short* __restrict__ biasB) {
  const int gid = blockIdx.x * blockDim.x + threadIdx.x;
  if (gid >= 12 * 13 * 13 * 256) return;
  const int r    = gid & 3;
  const int lane = (gid >> 2) & 63;
  const int t    = gid >> 8;          // (h*13 + mt)*13 + nt
  const int nt   = t % 13;
  const int mt   = (t / 13) % 13;
  const int h    = t / 169;
  const int q = mt * 16 + (lane & 15);
  const int k = nt * 16 + ((lane >> 4) & 3) * 4 + r;
  float v;
  if (q >= 197 || k >= 197) {
    v = -1e30f;
  } else {
    const unsigned short* rel = sm + 3072;
    const unsigned short* c2p = sm + 11820;
    const unsigned short* p2c = sm + 14172;
    const unsigned short* c2c = sm + 16524;
    unsigned short u;
    if (q == 0) {
      u = (k == 0) ? c2c[h] : c2p[h * 196 + (k - 1)];
    } else if (k == 0) {
      u = p2c[h * 196 + (q - 1)];
    } else {
      const int pi = q - 1, pj = k - 1;
      const int dh = pi / 14 - pj / 14 + 13;
      const int dw = pi % 14 - pj % 14 + 13;
      u = rel[(dh * 27 + dw) * 12 + h];
    }
    v = bf2f(u) * 1.4426950408889634f;
  }
  biasB[gid] = f2bf(v);
}

// ------------------------------------------------- transpose 768x768 + cvt
__global__ void transpose768_cvt(const void* __restrict__ in,
                                 unsigned short* __restrict__ out,
                                 const int* __restrict__ flag) {
  __shared__ unsigned short tile[32][33];
  const bool isf = (*flag != 0);
  const int tx = threadIdx.x & 31;
  const int ty = threadIdx.x >> 5;
  const int bx = blockIdx.x, by = blockIdx.y;
#pragma unroll
  for (int j = 0; j < 32; j += 8) {
    const size_t idx = (size_t)(by * 32 + ty + j) * CDIM + bx * 32 + tx;
    tile[ty + j][tx] = isf ? f2bf(((const float*)in)[idx])
                           : ((const unsigned short*)in)[idx];
  }
  __syncthreads();
#pragma unroll
  for (int j = 0; j < 32; j += 8)
    out[(size_t)(bx * 32 + ty + j) * CDIM + by * 32 + tx] = tile[tx][ty + j];
}

// ------------------------------------------------------------------- GEMM
// 1-D grid, bijective XCD-chunked remap (m204). Simple 2-barrier K-loop
// (round-4 structure, the proven one) but with BK=64: 12 iterations instead
// of 24 -> the per-iter barrier drain (the ~50% stall) is amortized 2x.
// 128-B LDS rows would be a 16-way ds_read conflict, so the tile is stored
// XOR-swizzled: gload_lds writes linearly while the GLOBAL source column is
// pre-permuted (((lane&7)^(lane>>3))*8), and ds_read applies the same XOR
// ((ql&7)<<4) -> optimal 8-slot x 8-lane distribution. LDS 32 KB.
__global__ __launch_bounds__(256, 2) void gemm_bt_bias(
    const unsigned short* __restrict__ A,
    const unsigned short* __restrict__ Bt,
    const unsigned short* __restrict__ bias,
    void* __restrict__ C,
    int M, int N, int K,
    const int* __restrict__ outf32) {
  __shared__ unsigned short As[128 * 64];   // 16 KB, swizzled 128-B rows
  __shared__ unsigned short Bs[128 * 64];   // 16 KB

  const int tid  = threadIdx.x;
  const int lane = tid & 63;
  const int wid  = tid >> 6;
  // XCD-aware bijective remap (nwg % 8 != 0 safe)
  const int nwg = gridDim.x;
  const int q8 = nwg >> 3, r8 = nwg & 7;
  const int xcd = blockIdx.x & 7, ii = blockIdx.x >> 3;
  const int wg = (xcd < r8 ? xcd * (q8 + 1) : r8 * (q8 + 1) + (xcd - r8) * q8) + ii;
  const int nbn = N >> 7;
  const int bm = wg / nbn, bn = wg % nbn;
  const int wm = wid >> 1, wn = wid & 1;
  const bool wf32 = (outf32 != nullptr) && (*outf32 != 0);

  // staging: wave w covers rows w*32 + j*8 + (lane>>3), j = 0..3.
  // source col pre-swizzled so linear LDS dest == swizzled layout.
  const int srow = wid * 32 + (lane >> 3);
  const int scol = ((lane & 7) ^ (lane >> 3)) * 8;
  const unsigned short* Ag = A  + (size_t)(bm * 128 + srow) * K + scol;
  const unsigned short* Bg = Bt + (size_t)(bn * 128 + srow) * K + scol;
  char* lA = (char*)As + wid * 4096;        // wave-uniform LDS bases
  char* lB = (char*)Bs + wid * 4096;

  const int ql = lane & 15, g = lane >> 4;
  const int fsw = ((ql & 7) << 4);          // frag read XOR

  f32x4 acc[4][4] = {};
  const int niter = K >> 6;                 // 12 for K=768

  for (int kt = 0; kt < niter; ++kt) {
#pragma unroll
    for (int j = 0; j < 4; ++j) {
      gload16(Ag + (size_t)(j * 8) * K, lA + j * 1024);
      gload16(Bg + (size_t)(j * 8) * K, lB + j * 1024);
    }
    Ag += 64; Bg += 64;
    __syncthreads();

#pragma unroll
    for (int kk = 0; kk < 2; ++kk) {
      bf16x8 fa[4], fb[4];
#pragma unroll
      for (int t = 0; t < 4; ++t) {
        const int ra = wm * 64 + t * 16 + ql;
        const int rb = wn * 64 + t * 16 + ql;
        fa[t] = *(const bf16x8*)((const char*)As + ra * 128 + ((kk * 64 + g * 16) ^ fsw));
        fb[t] = *(const bf16x8*)((const char*)Bs + rb * 128 + ((kk * 64 + g * 16) ^ fsw));
      }
#pragma unroll
      for (int mt = 0; mt < 4; ++mt)
#pragma unroll
        for (int c = 0; c < 4; ++c)
          acc[mt][c] = __builtin_amdgcn_mfma_f32_16x16x32_bf16(fa[mt], fb[c], acc[mt][c], 0, 0, 0);
    }
    __syncthreads();
  }

  // bias per column (hoisted)
  float bvv[4];
#pragma unroll
  for (int c = 0; c < 4; ++c)
    bvv[c] = bf2f(bias[bn * 128 + wn * 64 + c * 16 + ql]);

#pragma unroll
  for (int mt = 0; mt < 4; ++mt) {
    const int row0 = bm * 128 + wm * 64 + mt * 16 + g * 4;
#pragma unroll
    for (int r = 0; r < 4; ++r) {
      const size_t rowoff = (size_t)(row0 + r) * N + bn * 128 + wn * 64 + ql;
#pragma unroll
      for (int c = 0; c < 4; ++c) {
        const float val = acc[mt][c][r] + bvv[c];
        const size_t idx = rowoff + c * 16;
        if (wf32) ((float*)C)[idx] = val;
        else      ((unsigned short*)C)[idx] = f2bf(val);
      }
    }
  }
}

// ------------------------------------------------------- MFMA attention
// One block per (b,h), b-MAJOR: the 12 heads of one batch run adjacently so
// adjacent 128-B head-segments of each QKV/ctx row are read/written together
// (same L2 granule, same XCD, same time) -> no partial-line thrash.
// Swapped QK^T: s = mfma(K,Q) -> S^T frag (q = lane&15, k = nt*16 + g*4 + r).
// Softmax row lives in 4 lanes -> 2 shfl_xor per reduce; exp2-domain logits.
// P -> A-frag via cvt_pk_bf16 + ds_bpermute (no LDS round-trip, no fences).
// LDS 52.2 KB -> 3 blocks/CU.
__global__ __launch_bounds__(256, 3) void attn_mfma(
    const unsigned short* __restrict__ QKV,
    const unsigned short* __restrict__ biasB,
    unsigned short* __restrict__ ctx) {
  __shared__ unsigned short Kh[208 * 64];   // 26,624 B: 128-B rows, XOR-swizzled
  __shared__ unsigned short Vt[64 * VSTRD]; // 25,600 B: V^T [d][k], k-pad 200

  const int tid  = threadIdx.x;
  const int lane = tid & 63;
  const int wid  = tid >> 6;
  const int bh = blockIdx.x;
  const int b = bh / NH;          // b-major
  const int h = bh - b * NH;
  const size_t baseQ = (size_t)b * LSEQ * QKVS + (size_t)h * HD;
  const size_t baseK = baseQ + 768;
  const size_t baseV = baseQ + 1536;
  const size_t baseC = (size_t)b * LSEQ * CDIM + (size_t)h * HD;

  // stage K: packed 128-B rows, byte ^= (row&7)<<4 (2-way conflicts = free,
  // write pattern rows l..l+7 covers all 32 banks conflict-free)
  for (int i = tid; i < 197 * 8; i += 256) {
    const int l = i >> 3, c8 = (i & 7) * 8;
    const bf16x8 kv = *(const bf16x8*)&QKV[baseK + (size_t)l * QKVS + c8];
    *(bf16x8*)((char*)Kh + l * 128 + ((c8 * 2) ^ ((l & 7) << 4))) = kv;
  }
  // stage V^T
  for (int i = tid; i < 197 * 32; i += 256) {
    const int l = i >> 5, d2 = (i & 31) * 2;
    const unsigned vv = *(const unsigned*)&QKV[baseV + (size_t)l * QKVS + d2];
    Vt[d2 * VSTRD + l]       = (unsigned short)(vv & 0xffffu);
    Vt[(d2 + 1) * VSTRD + l] = (unsigned short)(vv >> 16);
  }
  // zero V^T pad cols k = 197..199 (t=6 tail reads k 192..199; P=0 past 196)
  for (int i = tid; i < 64 * 3; i += 256)
    Vt[(i / 3) * VSTRD + 197 + (i % 3)] = 0;
  __syncthreads();

  const int ql = lane & 15, g = lane >> 4;
  // K A-frag byte bases (swizzled); per-nt offset is the imm 2048*nt
  const int krd0 = ql * 128 + ((g * 16) ^ ((ql & 7) << 4));
  const int krd1 = ql * 128 + ((g * 16 + 64) ^ ((ql & 7) << 4));
  // V^T B-frag u16 bases
  const int vrd  = ql * VSTRD + g * 8;
  const int vrd6 = ql * VSTRD + 192;      // t=6 tail: clamp k-chunk to 192
  // bpermute source-lane byte addrs: g2a = 2*(g&1), g2b = g2a+1 (same q)
  const int addrA = (((g & 1) << 5) + ql) << 2;
  const int addrB = addrA + 64;
  const bool hi2 = lane >= 32;            // g >= 2
  const bool hi1 = lane >= 16;            // g >= 1

  for (int mt = wid; mt < 13; mt += 4) {
    // Q B-frags (global, 16B aligned; pad rows clamped to 196)
    const int qm = mt * 16 + ql;
    const unsigned short* qp =
        &QKV[baseQ + (size_t)(qm > 196 ? 196 : qm) * QKVS + g * 8];
    const bf16x8 qf0 = *(const bf16x8*)qp;
    const bf16x8 qf1 = *(const bf16x8*)(qp + 32);

    // bias quads: 13 coalesced dwordx2 bf16 (issued before MFMAs)
    const unsigned short* bp =
        biasB + (size_t)(h * 13 + mt) * 13 * 256 + (lane << 2);
    u16x4 bq[13];
#pragma unroll
    for (int nt = 0; nt < 13; ++nt) bq[nt] = *(const u16x4*)(bp + nt * 256);

    // S^T = K Q^T  (13 nt-tiles x 2 MFMAs)
    f32x4 s[13];
#pragma unroll
    for (int nt = 0; nt < 13; ++nt) {
      const bf16x8 kb0 = *(const bf16x8*)((const char*)Kh + nt * 2048 + krd0);
      const bf16x8 kb1 = *(const bf16x8*)((const char*)Kh + nt * 2048 + krd1);
      f32x4 a = {0.f, 0.f, 0.f, 0.f};
      a = __builtin_amdgcn_mfma_f32_16x16x32_bf16(kb0, qf0, a, 0, 0, 0);
      a = __builtin_amdgcn_mfma_f32_16x16x32_bf16(kb1, qf1, a, 0, 0, 0);
      s[nt] = a;
    }

    // log2-domain logits: s*(0.125*log2e) + bias*log2e
#pragma unroll
    for (int nt = 0; nt < 13; ++nt)
#pragma unroll
      for (int r = 0; r < 4; ++r)
        s[nt][r] = s[nt][r] * 0.18033688011112042f + bf2f(bq[nt][r]);

    // kill garbage K rows (k>=197 at nt=12) -- NaN-proof overwrite
    const float NEG = -1e30f;
    s[12][0] = hi2 ? NEG : s[12][0];
    s[12][1] = hi1 ? NEG : s[12][1];
    s[12][2] = hi1 ? NEG : s[12][2];
    s[12][3] = hi1 ? NEG : s[12][3];

    // exact softmax: row q spread over lanes {q, q+16, q+32, q+48}
    float m0 = s[0][0], m1 = s[0][1], m2 = s[0][2], m3 = s[0][3];
#pragma unroll
    for (int nt = 1; nt < 13; ++nt) {
      m0 = fmaxf(m0, s[nt][0]); m1 = fmaxf(m1, s[nt][1]);
      m2 = fmaxf(m2, s[nt][2]); m3 = fmaxf(m3, s[nt][3]);
    }
    float m = fmaxf(fmaxf(m0, m1), fmaxf(m2, m3));
    m = fmaxf(m, __shfl_xor(m, 16));
    m = fmaxf(m, __shfl_xor(m, 32));
    float t0 = 0.f, t1 = 0.f, t2 = 0.f, t3 = 0.f;
#pragma unroll
    for (int nt = 0; nt < 13; ++nt) {
      s[nt][0] = __builtin_exp2f(s[nt][0] - m); t0 += s[nt][0];
      s[nt][1] = __builtin_exp2f(s[nt][1] - m); t1 += s[nt][1];
      s[nt][2] = __builtin_exp2f(s[nt][2] - m); t2 += s[nt][2];
      s[nt][3] = __builtin_exp2f(s[nt][3] - m); t3 += s[nt][3];
    }
    float sum = (t0 + t1) + (t2 + t3);
    sum += __shfl_xor(sum, 16);
    sum += __shfl_xor(sum, 32);
    const float inv = __builtin_amdgcn_rcpf(sum);

    // normalize + pack P to bf16 pairs (k-adjacent): pk0 = (r0,r1), pk1 = (r2,r3)
    unsigned pk0[13], pk1[13];
#pragma unroll
    for (int nt = 0; nt < 13; ++nt) {
      const float p0 = s[nt][0] * inv, p1 = s[nt][1] * inv;
      const float p2 = s[nt][2] * inv, p3 = s[nt][3] * inv;
      unsigned lo, hi;
      asm("v_cvt_pk_bf16_f32 %0, %1, %2" : "=v"(lo) : "v"(p0), "v"(p1));
      asm("v_cvt_pk_bf16_f32 %0, %1, %2" : "=v"(hi) : "v"(p2), "v"(p3));
      pk0[nt] = lo; pk1[nt] = hi;
    }

    // O = P V : A-frag lane (g,q) needs k = t*32+g*8+j from lanes (2(g&1)(+1), q),
    // register nt = 2t + (g>>1) -> bpermute both nt candidates, select by hi2.
    f32x4 o[4] = {{0.f,0.f,0.f,0.f},{0.f,0.f,0.f,0.f},{0.f,0.f,0.f,0.f},{0.f,0.f,0.f,0.f}};
#pragma unroll
    for (int t = 0; t < 6; ++t) {
      const int i0 = 2 * t, i1 = 2 * t + 1;
      const int xA0 = __builtin_amdgcn_ds_bpermute(addrA, (int)pk0[i0]);
      const int yA0 = __builtin_amdgcn_ds_bpermute(addrA, (int)pk0[i1]);
      const int xA1 = __builtin_amdgcn_ds_bpermute(addrA, (int)pk1[i0]);
      const int yA1 = __builtin_amdgcn_ds_bpermute(addrA, (int)pk1[i1]);
      const int xB0 = __builtin_amdgcn_ds_bpermute(addrB, (int)pk0[i0]);
      const int yB0 = __builtin_amdgcn_ds_bpermute(addrB, (int)pk0[i1]);
      const int xB1 = __builtin_amdgcn_ds_bpermute(addrB, (int)pk1[i0]);
      const int yB1 = __builtin_amdgcn_ds_bpermute(addrB, (int)pk1[i1]);
      const bf16x8 pa = pack4((unsigned)(hi2 ? yA0 : xA0),
                              (unsigned)(hi2 ? yA1 : xA1),
                              (unsigned)(hi2 ? yB0 : xB0),
                              (unsigned)(hi2 ? yB1 : xB1));
#pragma unroll
      for (int ot = 0; ot < 4; ++ot) {
        const bf16x8 vbf = *(const bf16x8*)&Vt[ot * 16 * VSTRD + vrd + t * 32];
        o[ot] = __builtin_amdgcn_mfma_f32_16x16x32_bf16(pa, vbf, o[ot], 0, 0, 0);
      }
    }
    { // tail t=6: nt=12 only; g>=2 lanes are all-masked (P=0)
      const int xA0 = __builtin_amdgcn_ds_bpermute(addrA, (int)pk0[12]);
      const int xA1 = __builtin_amdgcn_ds_bpermute(addrA, (int)pk1[12]);
      const int xB0 = __builtin_amdgcn_ds_bpermute(addrB, (int)pk0[12]);
      const int xB1 = __builtin_amdgcn_ds_bpermute(addrB, (int)pk1[12]);
      const bf16x8 pa = pack4(hi2 ? 0u : (unsigned)xA0,
                              hi2 ? 0u : (unsigned)xA1,
                              hi2 ? 0u : (unsigned)xB0,
                              hi2 ? 0u : (unsigned)xB1);
#pragma unroll
      for (int ot = 0; ot < 4; ++ot) {
        const bf16x8 vbf = *(const bf16x8*)&Vt[ot * 16 * VSTRD + vrd6];
        o[ot] = __builtin_amdgcn_mfma_f32_16x16x32_bf16(pa, vbf, o[ot], 0, 0, 0);
      }
    }

    // store: complete each 128-B line (row q) in 4 consecutive 32-B stores
#pragma unroll
    for (int r = 0; r < 4; ++r) {
      const int q = mt * 16 + g * 4 + r;
      if (q < LSEQ) {
#pragma unroll
        for (int ot = 0; ot < 4; ++ot)
          ctx[baseC + (size_t)q * CDIM + ot * 16 + ql] = f2bf(o[ot][r]);
      }
    }
  }
}

// ------------------------------------------------------------------ launch
extern "C" void kernel_launch(void* const* d_in, const int* in_sizes, int n_in,
                              void* d_out, int out_size, void* d_ws, size_t ws_size,
                              hipStream_t stream) {
  const void* X   = d_in[0];
  const void* Wq  = d_in[1];
  const void* bq  = d_in[2];
  const void* Wk  = d_in[3];
  const void* bk  = d_in[4];
  const void* Wv  = d_in[5];
  const void* bv  = d_in[6];
  const void* Wo  = d_in[7];
  const void* bo  = d_in[8];
  const void* rel = d_in[9];
  const void* c2p = d_in[10];
  const void* p2c = d_in[11];
  const void* c2c = d_in[12];

  char* ws = (char*)d_ws;
  const size_t FLAG_OFF = 0;
  const size_t SM_OFF   = 256;                       // 16536 u16 = 33,072 B
  const size_t BIAS_OFF = 40960;                     // biasB: 519,168 u16 = 1,038,336 B
  const size_t WT_OFF   = BIAS_OFF + 2080768;        // aligned
  const size_t WT_SZ    = (size_t)CDIM * CDIM * 2;   // 1,179,648 B
  const size_t XB_OFF   = WT_OFF + 4 * WT_SZ;
  const size_t X_SZ     = (size_t)50432 * CDIM * 2;  // 77,463,552 B
  const size_t QKV_OFF  = XB_OFF + X_SZ;             // 50432*2304*2 = 232,390,656 B
  int* flag = (int*)(ws + FLAG_OFF);
  unsigned short* smb   = (unsigned short*)(ws + SM_OFF);
  unsigned short* biasB = (unsigned short*)(ws + BIAS_OFF);
  unsigned short* WqT = (unsigned short*)(ws + WT_OFF + 0 * WT_SZ);  // WqT|WkT|WvT
  unsigned short* WkT = (unsigned short*)(ws + WT_OFF + 1 * WT_SZ);  //   contiguous =
  unsigned short* WvT = (unsigned short*)(ws + WT_OFF + 2 * WT_SZ);  //   [2304][768]
  unsigned short* WoT = (unsigned short*)(ws + WT_OFF + 3 * WT_SZ);
  unsigned short* Xb  = (unsigned short*)(ws + XB_OFF);
  unsigned short* QKVb= (unsigned short*)(ws + QKV_OFF);
  unsigned short* Cb  = Xb;   // Xb dead after the QKV GEMM — reuse for ctx

  detect_dtype<<<1, 256, 0, stream>>>((const unsigned*)X, flag);

  convert_to_bf16<<<4096, 256, 0, stream>>>(X, Xb, flag, (long)50432 * CDIM);
  convert_small<<<65, 256, 0, stream>>>(bq, bk, bv, bo, rel, c2p, p2c, c2c, smb, flag);
  bias_build<<<2028, 256, 0, stream>>>(smb, biasB);

  dim3 tgrid(24, 24);
  transpose768_cvt<<<tgrid, 256, 0, stream>>>(Wq, WqT, flag);
  transpose768_cvt<<<tgrid, 256, 0, stream>>>(Wk, WkT, flag);
  transpose768_cvt<<<tgrid, 256, 0, stream>>>(Wv, WvT, flag);
  transpose768_cvt<<<tgrid, 256, 0, stream>>>(Wo, WoT, flag);

  // fused QKV GEMM: Bt = [WqT|WkT|WvT] (contiguous), bias = [bq|bk|bv] (contiguous)
  gemm_bt_bias<<<dim3(18 * 394), 256, 0, stream>>>(Xb, WqT, smb, QKVb,
                                                   50432, QKVS, CDIM, nullptr);

  attn_mfma<<<dim3(256 * NH), 256, 0, stream>>>(QKVb, biasB, Cb);

  gemm_bt_bias<<<dim3(6 * 394), 256, 0, stream>>>(Cb, WoT, smb + 2304, d_out,
                                                  50432, CDIM, CDIM, flag);
}